// Round 1
// baseline (1129.308 us; speedup 1.0000x reference)
//
#include <hip/hip_runtime.h>

#define S_LEN 3072
#define NHQ 16
#define NKVH 8
#define HDIM 256
#define WIN 2048
#define QKV_COLS 8192

typedef __bf16 bf16x8 __attribute__((ext_vector_type(8)));
typedef float f32x4 __attribute__((ext_vector_type(4)));

__device__ __forceinline__ unsigned short f2bf(float f) {
    union { float f; unsigned u; } v; v.f = f;
    unsigned r = v.u + 0x7FFFu + ((v.u >> 16) & 1u);
    return (unsigned short)(r >> 16);
}
__device__ __forceinline__ float bf2f(unsigned short u) {
    union { unsigned u; float f; } v; v.u = ((unsigned)u) << 16; return v.f;
}

typedef __attribute__((address_space(3))) void lds_void_t;
typedef const __attribute__((address_space(1))) void glb_void_t;
__device__ __forceinline__ void async16(const void* g, void* l) {
    __builtin_amdgcn_global_load_lds((glb_void_t*)g, (lds_void_t*)l, 16, 0, 0);
}

// ---------------- fp32 -> bf16 cast ----------------
__global__ __launch_bounds__(256) void cast_bf16_kernel(const float* __restrict__ src,
                                                        unsigned short* __restrict__ dst,
                                                        int n) {
    int i = (blockIdx.x * 256 + threadIdx.x) * 4;
    if (i >= n) return;
    float4 v = *(const float4*)(src + i);
    ushort4 o;
    o.x = f2bf(v.x); o.y = f2bf(v.y); o.z = f2bf(v.z); o.w = f2bf(v.w);
    *(ushort4*)(dst + i) = o;
}

// ---------------- bf16 GEMM: C[M,N] = A[M,K] @ B[N,K]^T ----------------
// m97 structure: 128x128 tile, BK=32, 4 waves each 64x64, global_load_lds w=16.
template <int OUT_BF16>
__global__ __launch_bounds__(256) void gemm_bt(const unsigned short* __restrict__ A,
                                               const unsigned short* __restrict__ B,
                                               void* __restrict__ Cv,
                                               int N, int K) {
    __shared__ __align__(16) unsigned short At[128 * 32];
    __shared__ __align__(16) unsigned short Bt[128 * 32];
    const int tid = threadIdx.x;
    const int wid = tid >> 6, lane = tid & 63;
    const int ln = lane & 15, quad = lane >> 4;
    const int bm = blockIdx.y, bn = blockIdx.x;
    const int wm = wid >> 1, wn = wid & 1;

    const f32x4 fzero = {0.f, 0.f, 0.f, 0.f};
    f32x4 acc[4][4];
#pragma unroll
    for (int i = 0; i < 4; i++) {
#pragma unroll
        for (int j = 0; j < 4; j++) acc[i][j] = fzero;
    }

    const unsigned short* gA = A + (size_t)(bm * 128 + wid * 32 + (lane >> 2)) * K + (lane & 3) * 8;
    const unsigned short* gB = B + (size_t)(bn * 128 + wid * 32 + (lane >> 2)) * K + (lane & 3) * 8;
    unsigned short* lA = At + wid * 32 * 32;
    unsigned short* lB = Bt + wid * 32 * 32;

    for (int k0 = 0; k0 < K; k0 += 32) {
        async16(gA + k0, lA);
        async16(gA + k0 + 16 * K, lA + 16 * 32);
        async16(gB + k0, lB);
        async16(gB + k0 + 16 * K, lB + 16 * 32);
        __syncthreads();   // drains vmcnt before LDS reads

        bf16x8 af[4], bfr[4];
#pragma unroll
        for (int mt = 0; mt < 4; mt++)
            af[mt] = *(const bf16x8*)(At + (wm * 64 + mt * 16 + ln) * 32 + quad * 8);
#pragma unroll
        for (int nt = 0; nt < 4; nt++)
            bfr[nt] = *(const bf16x8*)(Bt + (wn * 64 + nt * 16 + ln) * 32 + quad * 8);
#pragma unroll
        for (int mt = 0; mt < 4; mt++) {
#pragma unroll
            for (int nt = 0; nt < 4; nt++)
                acc[mt][nt] = __builtin_amdgcn_mfma_f32_16x16x32_bf16(af[mt], bfr[nt], acc[mt][nt], 0, 0, 0);
        }
        __syncthreads();
    }

    // C/D layout: col = lane&15, row = quad*4 + reg  [m89/m91 verified]
    const int row0 = bm * 128 + wm * 64 + quad * 4;
    const int col0 = bn * 128 + wn * 64 + ln;
    if (OUT_BF16) {
        unsigned short* C = (unsigned short*)Cv;
#pragma unroll
        for (int mt = 0; mt < 4; mt++) {
#pragma unroll
            for (int nt = 0; nt < 4; nt++) {
#pragma unroll
                for (int rr = 0; rr < 4; rr++)
                    C[(size_t)(row0 + mt * 16 + rr) * N + col0 + nt * 16] = f2bf(acc[mt][nt][rr]);
            }
        }
    } else {
        float* C = (float*)Cv;
#pragma unroll
        for (int mt = 0; mt < 4; mt++) {
#pragma unroll
            for (int nt = 0; nt < 4; nt++) {
#pragma unroll
                for (int rr = 0; rr < 4; rr++)
                    C[(size_t)(row0 + mt * 16 + rr) * N + col0 + nt * 16] = acc[mt][nt][rr];
            }
        }
    }
}

// ---------------- RoPE for Q (scaled) and K, scatter to [head][pos][dim] ----------------
__global__ __launch_bounds__(256) void rope_kernel(const unsigned short* __restrict__ qkv,
                                                   const float* __restrict__ freqs,
                                                   const int* __restrict__ kvidx,
                                                   unsigned short* __restrict__ Qb,
                                                   unsigned short* __restrict__ Kb) {
    int t = blockIdx.x * 256 + threadIdx.x;
    int d = t & 127;
    int t2 = t >> 7;
    int hh = t2 % 24;
    int pos = t2 / 24;
    if (pos >= S_LEN) return;
    float2 cs = *(const float2*)(freqs + ((size_t)pos * 128 + d) * 2);
    if (hh < NHQ) {
        const unsigned short* src = qkv + (size_t)pos * QKV_COLS + hh * HDIM + d;
        float x1 = bf2f(src[0]), x2 = bf2f(src[128]);
        float o1 = (x1 * cs.x - x2 * cs.y) * 0.0625f;  // QSCALE = 256^-0.5
        float o2 = (x1 * cs.y + x2 * cs.x) * 0.0625f;
        unsigned short* dst = Qb + ((size_t)hh * S_LEN + pos) * HDIM + d;
        dst[0] = f2bf(o1);
        dst[128] = f2bf(o2);
    } else {
        int kvh = hh - NHQ;
        const unsigned short* src = qkv + (size_t)pos * QKV_COLS + NHQ * HDIM + kvh * HDIM + d;
        float x1 = bf2f(src[0]), x2 = bf2f(src[128]);
        float o1 = x1 * cs.x - x2 * cs.y;
        float o2 = x1 * cs.y + x2 * cs.x;
        int wpos = kvidx[pos];
        unsigned short* dst = Kb + ((size_t)kvh * S_LEN + wpos) * HDIM + d;
        dst[0] = f2bf(o1);
        dst[128] = f2bf(o2);
    }
}

// ---------------- V transpose: qkv[pos][6144+c] -> Vbt[c][pos] (bf16) ----------------
__global__ __launch_bounds__(256) void vtrans_kernel(const unsigned short* __restrict__ qkv,
                                                     const int* __restrict__ kvidx,
                                                     unsigned short* __restrict__ Vbt) {
    __shared__ unsigned short T[64][72];
    int pos0 = blockIdx.x * 64;
    int c0 = blockIdx.y * 64;
    int a = threadIdx.x >> 6;
    int b = threadIdx.x & 63;
#pragma unroll
    for (int r = 0; r < 16; r++) {
        int pl = r * 4 + a;
        T[pl][b] = qkv[(size_t)(pos0 + pl) * QKV_COLS + 6144 + c0 + b];
    }
    __syncthreads();
    int wpos = kvidx[pos0 + b];
#pragma unroll
    for (int r = 0; r < 16; r++) {
        int cl = r * 4 + a;
        Vbt[(size_t)(c0 + cl) * S_LEN + wpos] = T[b][cl];
    }
}

// ---------------- flash attention: softcap + causal sliding window ----------------
// block = 4 waves; wave w owns q rows [q0+16w, q0+16w+16); BK=32 key tile.
__global__ __launch_bounds__(256) void attn_kernel(const unsigned short* __restrict__ Qb,
                                                   const unsigned short* __restrict__ Kb,
                                                   const unsigned short* __restrict__ Vbt,
                                                   unsigned short* __restrict__ attn_out) {
    __shared__ __align__(16) unsigned short Kl[32][264];  // pad: row stride 528B = +4 banks
    __shared__ __align__(16) unsigned short Vt[256][40];  // pad: row stride 80B
    __shared__ __align__(16) unsigned short Pl[4][16][40];

    const int qb = blockIdx.x, h = blockIdx.y;
    const int kv = h >> 1;
    const int q0 = qb * 64;
    const int tid = threadIdx.x;
    const int wid = tid >> 6, lane = tid & 63;
    const int ln = lane & 15, quad = lane >> 4;

    // Q fragments (A layout: m=lane&15, k=quad*8+j), 8 frags cover HD=256
    bf16x8 qf[8];
    {
        const unsigned short* qrow = Qb + ((size_t)h * S_LEN + q0 + wid * 16 + ln) * HDIM;
#pragma unroll
        for (int k0 = 0; k0 < 8; k0++)
            qf[k0] = *(const bf16x8*)(qrow + k0 * 32 + quad * 8);
    }

    const f32x4 fzero = {0.f, 0.f, 0.f, 0.f};
    f32x4 acc[16];
#pragma unroll
    for (int t = 0; t < 16; t++) acc[t] = fzero;
    float m_i[4] = {-1e30f, -1e30f, -1e30f, -1e30f};
    float l_i[4] = {0.f, 0.f, 0.f, 0.f};

    const int t_lo = (q0 > WIN - 1) ? ((q0 - (WIN - 1)) >> 5) : 0;
    const int t_hi = (q0 + 63) >> 5;
    const int irow = q0 + wid * 16 + quad * 4;

    const int krow = tid >> 3, kcs = (tid & 7) * 32;
    const unsigned short* ksrc0 = Kb + ((size_t)kv * S_LEN + krow) * HDIM + kcs;
    const unsigned short* vsrc0 = Vbt + ((size_t)kv * HDIM + tid) * S_LEN;

    for (int tt = t_lo; tt <= t_hi; tt++) {
        const int p0 = tt * 32;
        {
            const unsigned short* ks = ksrc0 + (size_t)p0 * HDIM;
            unsigned short* kd = &Kl[krow][kcs];
#pragma unroll
            for (int j = 0; j < 4; j++)
                *(uint4*)(kd + j * 8) = *(const uint4*)(ks + j * 8);
            const unsigned short* vs = vsrc0 + p0;
            unsigned short* vd = &Vt[tid][0];
#pragma unroll
            for (int j = 0; j < 4; j++)
                *(uint4*)(vd + j * 8) = *(const uint4*)(vs + j * 8);
        }
        __syncthreads();

        // S = Q K^T : two 16-col tiles
        f32x4 s0 = fzero, s1 = fzero;
#pragma unroll
        for (int k0 = 0; k0 < 8; k0++) {
            bf16x8 b0 = *(const bf16x8*)(&Kl[ln][k0 * 32 + quad * 8]);
            s0 = __builtin_amdgcn_mfma_f32_16x16x32_bf16(qf[k0], b0, s0, 0, 0, 0);
        }
#pragma unroll
        for (int k0 = 0; k0 < 8; k0++) {
            bf16x8 b1 = *(const bf16x8*)(&Kl[16 + ln][k0 * 32 + quad * 8]);
            s1 = __builtin_amdgcn_mfma_f32_16x16x32_bf16(qf[k0], b1, s1, 0, 0, 0);
        }

        float alpha_r[4];
#pragma unroll
        for (int r = 0; r < 4; r++) {
            const int i = irow + r;
            float sv0 = s0[r], sv1 = s1[r];
            {
                float x = fminf(fmaxf(sv0 * 0.02f, -15.f), 15.f);
                float e2 = __expf(x + x);
                sv0 = 50.f * (e2 - 1.f) / (e2 + 1.f);
                int j = p0 + ln;
                sv0 = ((j <= i) && (j + WIN > i)) ? sv0 : -2e30f;
            }
            {
                float x = fminf(fmaxf(sv1 * 0.02f, -15.f), 15.f);
                float e2 = __expf(x + x);
                sv1 = 50.f * (e2 - 1.f) / (e2 + 1.f);
                int j = p0 + 16 + ln;
                sv1 = ((j <= i) && (j + WIN > i)) ? sv1 : -2e30f;
            }
            float mx = fmaxf(sv0, sv1);
#pragma unroll
            for (int o = 8; o >= 1; o >>= 1)
                mx = fmaxf(mx, __shfl_xor(mx, o));
            const float mn = fmaxf(m_i[r], mx);
            alpha_r[r] = __expf(m_i[r] - mn);
            m_i[r] = mn;
            float p0v = __expf(sv0 - mn);   // masked: exp(-2e30 - (-1e30)) = 0
            float p1v = __expf(sv1 - mn);
            float rs = p0v + p1v;
#pragma unroll
            for (int o = 8; o >= 1; o >>= 1)
                rs += __shfl_xor(rs, o);
            l_i[r] = l_i[r] * alpha_r[r] + rs;
            // C-layout -> LDS (row = quad*4+r, col = key pos)
            Pl[wid][quad * 4 + r][ln] = f2bf(p0v);
            Pl[wid][quad * 4 + r][16 + ln] = f2bf(p1v);
        }
#pragma unroll
        for (int t = 0; t < 16; t++) {
            acc[t][0] *= alpha_r[0];
            acc[t][1] *= alpha_r[1];
            acc[t][2] *= alpha_r[2];
            acc[t][3] *= alpha_r[3];
        }
        // P back in A-layout (same wave: lgkmcnt ordering, no barrier needed)
        bf16x8 pa = *(const bf16x8*)(&Pl[wid][ln][quad * 8]);
#pragma unroll
        for (int t = 0; t < 16; t++) {
            bf16x8 vb = *(const bf16x8*)(&Vt[t * 16 + ln][quad * 8]);
            acc[t] = __builtin_amdgcn_mfma_f32_16x16x32_bf16(pa, vb, acc[t], 0, 0, 0);
        }
        __syncthreads();
    }

#pragma unroll
    for (int t = 0; t < 16; t++) {
#pragma unroll
        for (int r = 0; r < 4; r++) {
            float o = acc[t][r] / l_i[r];
            attn_out[(size_t)(irow + r) * 4096 + h * HDIM + t * 16 + ln] = f2bf(o);
        }
    }
}

// ---------------- launch ----------------
extern "C" void kernel_launch(void* const* d_in, const int* in_sizes, int n_in,
                              void* d_out, int out_size, void* d_ws, size_t ws_size,
                              hipStream_t stream) {
    (void)in_sizes; (void)n_in; (void)out_size; (void)ws_size;
    const float* hidden = (const float*)d_in[0];
    const float* freqs  = (const float*)d_in[1];
    const int* kvidx    = (const int*)d_in[2];
    // d_in[3]=k_cache, d_in[4]=v_cache (fully overwritten), d_in[5]=mask (recomputed): unused
    const float* qkv_w  = (const float*)d_in[6];
    const float* o_w    = (const float*)d_in[7];
    float* out = (float*)d_out;

    char* ws = (char*)d_ws;
    unsigned short* hs_bf   = (unsigned short*)(ws);                 // 22,020,096 B
    unsigned short* w1_bf   = (unsigned short*)(ws + 22020096);      // 58,720,256 B
    unsigned short* w2_bf   = (unsigned short*)(ws + 80740352);      // 29,360,128 B
    unsigned short* qkv_bf  = (unsigned short*)(ws + 110100480);     // 50,331,648 B
    unsigned short* Qb      = (unsigned short*)(ws + 160432128);     // 25,165,824 B
    unsigned short* Kb      = (unsigned short*)(ws + 185597952);     // 12,582,912 B
    unsigned short* Vbt     = (unsigned short*)(ws + 198180864);     // 12,582,912 B
    unsigned short* attn_bf = (unsigned short*)(ws + 210763776);     // 25,165,824 B  (total 235,929,600)

    cast_bf16_kernel<<<10752, 256, 0, stream>>>(hidden, hs_bf, 11010048);
    cast_bf16_kernel<<<28672, 256, 0, stream>>>(qkv_w, w1_bf, 29360128);
    cast_bf16_kernel<<<14336, 256, 0, stream>>>(o_w, w2_bf, 14680064);

    gemm_bt<1><<<dim3(64, 24), 256, 0, stream>>>(hs_bf, w1_bf, (void*)qkv_bf, 8192, 3584);

    rope_kernel<<<36864, 256, 0, stream>>>(qkv_bf, freqs, kvidx, Qb, Kb);
    vtrans_kernel<<<dim3(48, 32), 256, 0, stream>>>(qkv_bf, kvidx, Vbt);

    attn_kernel<<<dim3(48, 16), 256, 0, stream>>>(Qb, Kb, Vbt, attn_bf);

    gemm_bt<0><<<dim3(28, 24), 256, 0, stream>>>(attn_bf, w2_bf, (void*)out, 3584, 4096);
}

// Round 2
// 954.219 us; speedup vs baseline: 1.1835x; 1.1835x over previous
//
#include <hip/hip_runtime.h>

#define S_LEN 3072
#define NHQ 16
#define NKVH 8
#define HDIM 256
#define WIN 2048
#define QKV_COLS 8192

typedef __bf16 bf16x8 __attribute__((ext_vector_type(8)));
typedef float f32x4 __attribute__((ext_vector_type(4)));

__device__ __forceinline__ unsigned short f2bf(float f) {
    union { float f; unsigned u; } v; v.f = f;
    unsigned r = v.u + 0x7FFFu + ((v.u >> 16) & 1u);
    return (unsigned short)(r >> 16);
}
__device__ __forceinline__ float bf2f(unsigned short u) {
    union { unsigned u; float f; } v; v.u = ((unsigned)u) << 16; return v.f;
}

typedef __attribute__((address_space(3))) void lds_void_t;
typedef const __attribute__((address_space(1))) void glb_void_t;
__device__ __forceinline__ void async16(const void* g, void* l) {
    __builtin_amdgcn_global_load_lds((glb_void_t*)g, (lds_void_t*)l, 16, 0, 0);
}

// ---------------- fp32 -> bf16 cast ----------------
__global__ __launch_bounds__(256) void cast_bf16_kernel(const float* __restrict__ src,
                                                        unsigned short* __restrict__ dst,
                                                        int n) {
    int i = (blockIdx.x * 256 + threadIdx.x) * 4;
    if (i >= n) return;
    float4 v = *(const float4*)(src + i);
    ushort4 o;
    o.x = f2bf(v.x); o.y = f2bf(v.y); o.z = f2bf(v.z); o.w = f2bf(v.w);
    *(ushort4*)(dst + i) = o;
}

// ---------------- bf16 GEMM: C[M,N] = A[M,K] @ B[N,K]^T ----------------
template <int OUT_BF16>
__global__ __launch_bounds__(256) void gemm_bt(const unsigned short* __restrict__ A,
                                               const unsigned short* __restrict__ B,
                                               void* __restrict__ Cv,
                                               int N, int K) {
    __shared__ __align__(16) unsigned short At[128 * 32];
    __shared__ __align__(16) unsigned short Bt[128 * 32];
    const int tid = threadIdx.x;
    const int wid = tid >> 6, lane = tid & 63;
    const int ln = lane & 15, quad = lane >> 4;
    const int bm = blockIdx.y, bn = blockIdx.x;
    const int wm = wid >> 1, wn = wid & 1;

    const f32x4 fzero = {0.f, 0.f, 0.f, 0.f};
    f32x4 acc[4][4];
#pragma unroll
    for (int i = 0; i < 4; i++) {
#pragma unroll
        for (int j = 0; j < 4; j++) acc[i][j] = fzero;
    }

    const unsigned short* gA = A + (size_t)(bm * 128 + wid * 32 + (lane >> 2)) * K + (lane & 3) * 8;
    const unsigned short* gB = B + (size_t)(bn * 128 + wid * 32 + (lane >> 2)) * K + (lane & 3) * 8;
    unsigned short* lA = At + wid * 32 * 32;
    unsigned short* lB = Bt + wid * 32 * 32;

    for (int k0 = 0; k0 < K; k0 += 32) {
        async16(gA + k0, lA);
        async16(gA + k0 + 16 * K, lA + 16 * 32);
        async16(gB + k0, lB);
        async16(gB + k0 + 16 * K, lB + 16 * 32);
        __syncthreads();

        bf16x8 af[4], bfr[4];
#pragma unroll
        for (int mt = 0; mt < 4; mt++)
            af[mt] = *(const bf16x8*)(At + (wm * 64 + mt * 16 + ln) * 32 + quad * 8);
#pragma unroll
        for (int nt = 0; nt < 4; nt++)
            bfr[nt] = *(const bf16x8*)(Bt + (wn * 64 + nt * 16 + ln) * 32 + quad * 8);
#pragma unroll
        for (int mt = 0; mt < 4; mt++) {
#pragma unroll
            for (int nt = 0; nt < 4; nt++)
                acc[mt][nt] = __builtin_amdgcn_mfma_f32_16x16x32_bf16(af[mt], bfr[nt], acc[mt][nt], 0, 0, 0);
        }
        __syncthreads();
    }

    const int row0 = bm * 128 + wm * 64 + quad * 4;
    const int col0 = bn * 128 + wn * 64 + ln;
    if (OUT_BF16) {
        unsigned short* C = (unsigned short*)Cv;
#pragma unroll
        for (int mt = 0; mt < 4; mt++) {
#pragma unroll
            for (int nt = 0; nt < 4; nt++) {
#pragma unroll
                for (int rr = 0; rr < 4; rr++)
                    C[(size_t)(row0 + mt * 16 + rr) * N + col0 + nt * 16] = f2bf(acc[mt][nt][rr]);
            }
        }
    } else {
        float* C = (float*)Cv;
#pragma unroll
        for (int mt = 0; mt < 4; mt++) {
#pragma unroll
            for (int nt = 0; nt < 4; nt++) {
#pragma unroll
                for (int rr = 0; rr < 4; rr++)
                    C[(size_t)(row0 + mt * 16 + rr) * N + col0 + nt * 16] = acc[mt][nt][rr];
            }
        }
    }
}

// ---------------- RoPE for Q (scaled) and K ----------------
__global__ __launch_bounds__(256) void rope_kernel(const unsigned short* __restrict__ qkv,
                                                   const float* __restrict__ freqs,
                                                   const int* __restrict__ kvidx,
                                                   unsigned short* __restrict__ Qb,
                                                   unsigned short* __restrict__ Kb) {
    int t = blockIdx.x * 256 + threadIdx.x;
    int d = t & 127;
    int t2 = t >> 7;
    int hh = t2 % 24;
    int pos = t2 / 24;
    if (pos >= S_LEN) return;
    float2 cs = *(const float2*)(freqs + ((size_t)pos * 128 + d) * 2);
    if (hh < NHQ) {
        const unsigned short* src = qkv + (size_t)pos * QKV_COLS + hh * HDIM + d;
        float x1 = bf2f(src[0]), x2 = bf2f(src[128]);
        float o1 = (x1 * cs.x - x2 * cs.y) * 0.0625f;
        float o2 = (x1 * cs.y + x2 * cs.x) * 0.0625f;
        unsigned short* dst = Qb + ((size_t)hh * S_LEN + pos) * HDIM + d;
        dst[0] = f2bf(o1);
        dst[128] = f2bf(o2);
    } else {
        int kvh = hh - NHQ;
        const unsigned short* src = qkv + (size_t)pos * QKV_COLS + NHQ * HDIM + kvh * HDIM + d;
        float x1 = bf2f(src[0]), x2 = bf2f(src[128]);
        float o1 = x1 * cs.x - x2 * cs.y;
        float o2 = x1 * cs.y + x2 * cs.x;
        int wpos = kvidx[pos];
        unsigned short* dst = Kb + ((size_t)kvh * S_LEN + wpos) * HDIM + d;
        dst[0] = f2bf(o1);
        dst[128] = f2bf(o2);
    }
}

// ---------------- V transpose ----------------
__global__ __launch_bounds__(256) void vtrans_kernel(const unsigned short* __restrict__ qkv,
                                                     const int* __restrict__ kvidx,
                                                     unsigned short* __restrict__ Vbt) {
    __shared__ unsigned short T[64][72];
    int pos0 = blockIdx.x * 64;
    int c0 = blockIdx.y * 64;
    int a = threadIdx.x >> 6;
    int b = threadIdx.x & 63;
#pragma unroll
    for (int r = 0; r < 16; r++) {
        int pl = r * 4 + a;
        T[pl][b] = qkv[(size_t)(pos0 + pl) * QKV_COLS + 6144 + c0 + b];
    }
    __syncthreads();
    int wpos = kvidx[pos0 + b];
#pragma unroll
    for (int r = 0; r < 16; r++) {
        int cl = r * 4 + a;
        Vbt[(size_t)(c0 + cl) * S_LEN + wpos] = T[b][cl];
    }
}

// ---------------- flash attention v2: fixed-max softmax ----------------
// Softcap bounds scores to [-50,50], so p = exp(score) needs no running max:
// p in [e^-50, e^50], sums < 1e25 (fp32-safe), softmax ratios unchanged.
// Removes per-tile shuffle reductions, acc rescale, and online-max exps.
__global__ __launch_bounds__(256) void attn_kernel(const unsigned short* __restrict__ Qb,
                                                   const unsigned short* __restrict__ Kb,
                                                   const unsigned short* __restrict__ Vbt,
                                                   unsigned short* __restrict__ attn_out) {
    __shared__ __align__(16) unsigned short Kl[32][264];
    __shared__ __align__(16) unsigned short Vt[256][40];
    __shared__ __align__(16) unsigned short Pl[4][16][40];

    const int qb = blockIdx.x, h = blockIdx.y;
    const int kv = h >> 1;
    const int q0 = qb * 64;
    const int tid = threadIdx.x;
    const int wid = tid >> 6, lane = tid & 63;
    const int ln = lane & 15, quad = lane >> 4;

    bf16x8 qf[8];
    {
        const unsigned short* qrow = Qb + ((size_t)h * S_LEN + q0 + wid * 16 + ln) * HDIM;
#pragma unroll
        for (int k0 = 0; k0 < 8; k0++)
            qf[k0] = *(const bf16x8*)(qrow + k0 * 32 + quad * 8);
    }

    const f32x4 fzero = {0.f, 0.f, 0.f, 0.f};
    f32x4 acc[16];
#pragma unroll
    for (int t = 0; t < 16; t++) acc[t] = fzero;
    float ps[4] = {0.f, 0.f, 0.f, 0.f};

    const int imin = q0 + wid * 16;        // wave's min q row
    const int imax = imin + 15;            // wave's max q row
    const int irow = imin + quad * 4;

    const int t_lo = (q0 > WIN - 1) ? ((q0 - (WIN - 1)) >> 5) : 0;
    const int t_hi = (q0 + 63) >> 5;

    const int krow = tid >> 3, kcs = (tid & 7) * 32;
    const unsigned short* ksrc0 = Kb + ((size_t)kv * S_LEN + krow) * HDIM + kcs;
    const unsigned short* vsrc0 = Vbt + ((size_t)kv * HDIM + tid) * S_LEN;

    for (int tt = t_lo; tt <= t_hi; tt++) {
        const int p0 = tt * 32;
        {
            const unsigned short* ks = ksrc0 + (size_t)p0 * HDIM;
            unsigned short* kd = &Kl[krow][kcs];
#pragma unroll
            for (int j = 0; j < 4; j++)
                *(uint4*)(kd + j * 8) = *(const uint4*)(ks + j * 8);
            const unsigned short* vs = vsrc0 + p0;
            unsigned short* vd = &Vt[tid][0];
#pragma unroll
            for (int j = 0; j < 4; j++)
                *(uint4*)(vd + j * 8) = *(const uint4*)(vs + j * 8);
        }
        __syncthreads();

        // wave-level skip of fully-masked edge tiles (wave-uniform, barrier-safe)
        const bool live = (p0 <= imax) && (p0 + 31 >= imin - WIN + 1);
        if (live) {
            f32x4 s0 = fzero, s1 = fzero;
#pragma unroll
            for (int k0 = 0; k0 < 8; k0++) {
                bf16x8 b0 = *(const bf16x8*)(&Kl[ln][k0 * 32 + quad * 8]);
                s0 = __builtin_amdgcn_mfma_f32_16x16x32_bf16(qf[k0], b0, s0, 0, 0, 0);
            }
#pragma unroll
            for (int k0 = 0; k0 < 8; k0++) {
                bf16x8 b1 = *(const bf16x8*)(&Kl[16 + ln][k0 * 32 + quad * 8]);
                s1 = __builtin_amdgcn_mfma_f32_16x16x32_bf16(qf[k0], b1, s1, 0, 0, 0);
            }

            // tile fully inside the causal sliding window? (wave-uniform)
            const bool full = (p0 + 31 <= imin) && (p0 >= imax - WIN + 1);
#pragma unroll
            for (int r = 0; r < 4; r++) {
                // p = exp(50*tanh(s/50)) via z=e^{2s/50}: tanh = 1 - 2/(z+1)
                float z0 = __expf(s0[r] * 0.04f);
                float z1 = __expf(s1[r] * 0.04f);
                float t0 = fmaf(-100.f, __builtin_amdgcn_rcpf(z0 + 1.f), 50.f);
                float t1 = fmaf(-100.f, __builtin_amdgcn_rcpf(z1 + 1.f), 50.f);
                float p0v = __expf(t0);
                float p1v = __expf(t1);
                if (!full) {
                    const int i = irow + r;
                    int j0 = p0 + ln, j1 = p0 + 16 + ln;
                    p0v = ((j0 <= i) && (j0 + WIN > i)) ? p0v : 0.f;
                    p1v = ((j1 <= i) && (j1 + WIN > i)) ? p1v : 0.f;
                }
                ps[r] += p0v + p1v;
                Pl[wid][quad * 4 + r][ln] = f2bf(p0v);
                Pl[wid][quad * 4 + r][16 + ln] = f2bf(p1v);
            }
            bf16x8 pa = *(const bf16x8*)(&Pl[wid][ln][quad * 8]);
#pragma unroll
            for (int t = 0; t < 16; t++) {
                bf16x8 vb = *(const bf16x8*)(&Vt[t * 16 + ln][quad * 8]);
                acc[t] = __builtin_amdgcn_mfma_f32_16x16x32_bf16(pa, vb, acc[t], 0, 0, 0);
            }
        }
        __syncthreads();
    }

    float inv[4];
#pragma unroll
    for (int r = 0; r < 4; r++) {
        float s = ps[r];
#pragma unroll
        for (int o = 1; o <= 8; o <<= 1)
            s += __shfl_xor(s, o);
        inv[r] = __builtin_amdgcn_rcpf(s);
    }
#pragma unroll
    for (int t = 0; t < 16; t++) {
#pragma unroll
        for (int r = 0; r < 4; r++) {
            float o = acc[t][r] * inv[r];
            attn_out[(size_t)(irow + r) * 4096 + h * HDIM + t * 16 + ln] = f2bf(o);
        }
    }
}

// ---------------- launch ----------------
extern "C" void kernel_launch(void* const* d_in, const int* in_sizes, int n_in,
                              void* d_out, int out_size, void* d_ws, size_t ws_size,
                              hipStream_t stream) {
    (void)in_sizes; (void)n_in; (void)out_size; (void)ws_size;
    const float* hidden = (const float*)d_in[0];
    const float* freqs  = (const float*)d_in[1];
    const int* kvidx    = (const int*)d_in[2];
    const float* qkv_w  = (const float*)d_in[6];
    const float* o_w    = (const float*)d_in[7];
    float* out = (float*)d_out;

    char* ws = (char*)d_ws;
    unsigned short* hs_bf   = (unsigned short*)(ws);
    unsigned short* w1_bf   = (unsigned short*)(ws + 22020096);
    unsigned short* w2_bf   = (unsigned short*)(ws + 80740352);
    unsigned short* qkv_bf  = (unsigned short*)(ws + 110100480);
    unsigned short* Qb      = (unsigned short*)(ws + 160432128);
    unsigned short* Kb      = (unsigned short*)(ws + 185597952);
    unsigned short* Vbt     = (unsigned short*)(ws + 198180864);
    unsigned short* attn_bf = (unsigned short*)(ws + 210763776);

    cast_bf16_kernel<<<10752, 256, 0, stream>>>(hidden, hs_bf, 11010048);
    cast_bf16_kernel<<<28672, 256, 0, stream>>>(qkv_w, w1_bf, 29360128);
    cast_bf16_kernel<<<14336, 256, 0, stream>>>(o_w, w2_bf, 14680064);

    gemm_bt<1><<<dim3(64, 24), 256, 0, stream>>>(hs_bf, w1_bf, (void*)qkv_bf, 8192, 3584);

    rope_kernel<<<36864, 256, 0, stream>>>(qkv_bf, freqs, kvidx, Qb, Kb);
    vtrans_kernel<<<dim3(48, 32), 256, 0, stream>>>(qkv_bf, kvidx, Vbt);

    attn_kernel<<<dim3(48, 16), 256, 0, stream>>>(Qb, Kb, Vbt, attn_bf);

    gemm_bt<0><<<dim3(28, 24), 256, 0, stream>>>(attn_bf, w2_bf, (void*)out, 3584, 4096);
}

// Round 3
// 942.686 us; speedup vs baseline: 1.1980x; 1.0122x over previous
//
#include <hip/hip_runtime.h>

#define S_LEN 3072
#define NHQ 16
#define NKVH 8
#define HDIM 256
#define WIN 2048
#define QKV_COLS 8192

typedef __bf16 bf16x8 __attribute__((ext_vector_type(8)));
typedef float f32x4 __attribute__((ext_vector_type(4)));

__device__ __forceinline__ unsigned short f2bf(float f) {
    union { float f; unsigned u; } v; v.f = f;
    unsigned r = v.u + 0x7FFFu + ((v.u >> 16) & 1u);
    return (unsigned short)(r >> 16);
}
__device__ __forceinline__ float bf2f(unsigned short u) {
    union { unsigned u; float f; } v; v.u = ((unsigned)u) << 16; return v.f;
}

typedef __attribute__((address_space(3))) void lds_void_t;
typedef const __attribute__((address_space(1))) void glb_void_t;
__device__ __forceinline__ void async16(const void* g, void* l) {
    __builtin_amdgcn_global_load_lds((glb_void_t*)g, (lds_void_t*)l, 16, 0, 0);
}

// ---------------- fp32 -> bf16 cast ----------------
__global__ __launch_bounds__(256) void cast_bf16_kernel(const float* __restrict__ src,
                                                        unsigned short* __restrict__ dst,
                                                        int n) {
    int i = (blockIdx.x * 256 + threadIdx.x) * 4;
    if (i >= n) return;
    float4 v = *(const float4*)(src + i);
    ushort4 o;
    o.x = f2bf(v.x); o.y = f2bf(v.y); o.z = f2bf(v.z); o.w = f2bf(v.w);
    *(ushort4*)(dst + i) = o;
}

// ---------------- bf16 GEMM: C[M,N] = A[M,K] @ B[N,K]^T ----------------
template <int OUT_BF16>
__global__ __launch_bounds__(256) void gemm_bt(const unsigned short* __restrict__ A,
                                               const unsigned short* __restrict__ B,
                                               void* __restrict__ Cv,
                                               int N, int K) {
    __shared__ __align__(16) unsigned short At[128 * 32];
    __shared__ __align__(16) unsigned short Bt[128 * 32];
    const int tid = threadIdx.x;
    const int wid = tid >> 6, lane = tid & 63;
    const int ln = lane & 15, quad = lane >> 4;
    const int bm = blockIdx.y, bn = blockIdx.x;
    const int wm = wid >> 1, wn = wid & 1;

    const f32x4 fzero = {0.f, 0.f, 0.f, 0.f};
    f32x4 acc[4][4];
#pragma unroll
    for (int i = 0; i < 4; i++) {
#pragma unroll
        for (int j = 0; j < 4; j++) acc[i][j] = fzero;
    }

    const unsigned short* gA = A + (size_t)(bm * 128 + wid * 32 + (lane >> 2)) * K + (lane & 3) * 8;
    const unsigned short* gB = B + (size_t)(bn * 128 + wid * 32 + (lane >> 2)) * K + (lane & 3) * 8;
    unsigned short* lA = At + wid * 32 * 32;
    unsigned short* lB = Bt + wid * 32 * 32;

    for (int k0 = 0; k0 < K; k0 += 32) {
        async16(gA + k0, lA);
        async16(gA + k0 + 16 * K, lA + 16 * 32);
        async16(gB + k0, lB);
        async16(gB + k0 + 16 * K, lB + 16 * 32);
        __syncthreads();

        bf16x8 af[4], bfr[4];
#pragma unroll
        for (int mt = 0; mt < 4; mt++)
            af[mt] = *(const bf16x8*)(At + (wm * 64 + mt * 16 + ln) * 32 + quad * 8);
#pragma unroll
        for (int nt = 0; nt < 4; nt++)
            bfr[nt] = *(const bf16x8*)(Bt + (wn * 64 + nt * 16 + ln) * 32 + quad * 8);
#pragma unroll
        for (int mt = 0; mt < 4; mt++) {
#pragma unroll
            for (int nt = 0; nt < 4; nt++)
                acc[mt][nt] = __builtin_amdgcn_mfma_f32_16x16x32_bf16(af[mt], bfr[nt], acc[mt][nt], 0, 0, 0);
        }
        __syncthreads();
    }

    const int row0 = bm * 128 + wm * 64 + quad * 4;
    const int col0 = bn * 128 + wn * 64 + ln;
    if (OUT_BF16) {
        unsigned short* C = (unsigned short*)Cv;
#pragma unroll
        for (int mt = 0; mt < 4; mt++) {
#pragma unroll
            for (int nt = 0; nt < 4; nt++) {
#pragma unroll
                for (int rr = 0; rr < 4; rr++)
                    C[(size_t)(row0 + mt * 16 + rr) * N + col0 + nt * 16] = f2bf(acc[mt][nt][rr]);
            }
        }
    } else {
        float* C = (float*)Cv;
#pragma unroll
        for (int mt = 0; mt < 4; mt++) {
#pragma unroll
            for (int nt = 0; nt < 4; nt++) {
#pragma unroll
                for (int rr = 0; rr < 4; rr++)
                    C[(size_t)(row0 + mt * 16 + rr) * N + col0 + nt * 16] = acc[mt][nt][rr];
            }
        }
    }
}

// ---------------- RoPE for Q (scaled) and K ----------------
__global__ __launch_bounds__(256) void rope_kernel(const unsigned short* __restrict__ qkv,
                                                   const float* __restrict__ freqs,
                                                   const int* __restrict__ kvidx,
                                                   unsigned short* __restrict__ Qb,
                                                   unsigned short* __restrict__ Kb) {
    int t = blockIdx.x * 256 + threadIdx.x;
    int d = t & 127;
    int t2 = t >> 7;
    int hh = t2 % 24;
    int pos = t2 / 24;
    if (pos >= S_LEN) return;
    float2 cs = *(const float2*)(freqs + ((size_t)pos * 128 + d) * 2);
    if (hh < NHQ) {
        const unsigned short* src = qkv + (size_t)pos * QKV_COLS + hh * HDIM + d;
        float x1 = bf2f(src[0]), x2 = bf2f(src[128]);
        float o1 = (x1 * cs.x - x2 * cs.y) * 0.0625f;
        float o2 = (x1 * cs.y + x2 * cs.x) * 0.0625f;
        unsigned short* dst = Qb + ((size_t)hh * S_LEN + pos) * HDIM + d;
        dst[0] = f2bf(o1);
        dst[128] = f2bf(o2);
    } else {
        int kvh = hh - NHQ;
        const unsigned short* src = qkv + (size_t)pos * QKV_COLS + NHQ * HDIM + kvh * HDIM + d;
        float x1 = bf2f(src[0]), x2 = bf2f(src[128]);
        float o1 = x1 * cs.x - x2 * cs.y;
        float o2 = x1 * cs.y + x2 * cs.x;
        int wpos = kvidx[pos];
        unsigned short* dst = Kb + ((size_t)kvh * S_LEN + wpos) * HDIM + d;
        dst[0] = f2bf(o1);
        dst[128] = f2bf(o2);
    }
}

// ---------------- V transpose ----------------
__global__ __launch_bounds__(256) void vtrans_kernel(const unsigned short* __restrict__ qkv,
                                                     const int* __restrict__ kvidx,
                                                     unsigned short* __restrict__ Vbt) {
    __shared__ unsigned short T[64][72];
    int pos0 = blockIdx.x * 64;
    int c0 = blockIdx.y * 64;
    int a = threadIdx.x >> 6;
    int b = threadIdx.x & 63;
#pragma unroll
    for (int r = 0; r < 16; r++) {
        int pl = r * 4 + a;
        T[pl][b] = qkv[(size_t)(pos0 + pl) * QKV_COLS + 6144 + c0 + b];
    }
    __syncthreads();
    int wpos = kvidx[pos0 + b];
#pragma unroll
    for (int r = 0; r < 16; r++) {
        int cl = r * 4 + a;
        Vbt[(size_t)(c0 + cl) * S_LEN + wpos] = T[b][cl];
    }
}

// ---------------- flash attention v3: key-chunked for parallelism ----------------
// 1536 blocks: (h, qb, chunk). Chunks of <=32 key-tiles (balanced split).
// Fixed-max softmax (softcap bounds scores) => partial (acc, ps) combine by
// pure addition: fp32 atomicAdd into Acc/Ps for multi-chunk rows; single-chunk
// rows (pos < 1024) write attn_bf directly.
__global__ __launch_bounds__(256) void attn_kernel(const unsigned short* __restrict__ Qb,
                                                   const unsigned short* __restrict__ Kb,
                                                   const unsigned short* __restrict__ Vbt,
                                                   float* __restrict__ Acc,
                                                   float* __restrict__ Ps,
                                                   unsigned short* __restrict__ attn_out) {
    __shared__ __align__(16) unsigned short Kl[32][264];
    __shared__ __align__(16) unsigned short Vt[256][40];
    __shared__ __align__(16) unsigned short Pl[4][16][40];

    // decode (h, qb, chunk) — reversed so long chunks dispatch first
    const int h = blockIdx.x / 96;
    const int it = 95 - (blockIdx.x % 96);
    int qb, sub, nc;
    if (it < 16)      { qb = it; sub = 0; nc = 1; }
    else if (it < 48) { int e = it - 16; qb = 16 + (e >> 1); sub = e & 1; nc = 2; }
    else              { int e = it - 48; qb = 32 + e / 3; sub = e % 3; nc = 3; }

    const int kv = h >> 1;
    const int q0 = qb * 64;
    const int tid = threadIdx.x;
    const int wid = tid >> 6, lane = tid & 63;
    const int ln = lane & 15, quad = lane >> 4;

    bf16x8 qf[8];
    {
        const unsigned short* qrow = Qb + ((size_t)h * S_LEN + q0 + wid * 16 + ln) * HDIM;
#pragma unroll
        for (int k0 = 0; k0 < 8; k0++)
            qf[k0] = *(const bf16x8*)(qrow + k0 * 32 + quad * 8);
    }

    const f32x4 fzero = {0.f, 0.f, 0.f, 0.f};
    f32x4 acc[16];
#pragma unroll
    for (int t = 0; t < 16; t++) acc[t] = fzero;
    float ps[4] = {0.f, 0.f, 0.f, 0.f};

    const int imin = q0 + wid * 16;
    const int imax = imin + 15;
    const int irow = imin + quad * 4;

    const int t_lo = (q0 >= WIN) ? ((q0 - (WIN - 1)) >> 5) : 0;
    const int t_hi = (q0 + 63) >> 5;
    const int tn = t_hi - t_lo + 1;
    const int ts = t_lo + (tn * sub) / nc;
    const int te = t_lo + (tn * (sub + 1)) / nc;

    const int krow = tid >> 3, kcs = (tid & 7) * 32;
    const unsigned short* ksrc0 = Kb + ((size_t)kv * S_LEN + krow) * HDIM + kcs;
    const unsigned short* vsrc0 = Vbt + ((size_t)kv * HDIM + tid) * S_LEN;

    for (int tt = ts; tt < te; tt++) {
        const int p0 = tt * 32;
        {
            const unsigned short* ks = ksrc0 + (size_t)p0 * HDIM;
            unsigned short* kd = &Kl[krow][kcs];
#pragma unroll
            for (int j = 0; j < 4; j++)
                *(uint4*)(kd + j * 8) = *(const uint4*)(ks + j * 8);
            const unsigned short* vs = vsrc0 + p0;
            unsigned short* vd = &Vt[tid][0];
#pragma unroll
            for (int j = 0; j < 4; j++)
                *(uint4*)(vd + j * 8) = *(const uint4*)(vs + j * 8);
        }
        __syncthreads();

        const bool live = (p0 <= imax) && (p0 + 31 >= imin - WIN + 1);
        if (live) {
            f32x4 s0 = fzero, s1 = fzero;
#pragma unroll
            for (int k0 = 0; k0 < 8; k0++) {
                bf16x8 b0 = *(const bf16x8*)(&Kl[ln][k0 * 32 + quad * 8]);
                s0 = __builtin_amdgcn_mfma_f32_16x16x32_bf16(qf[k0], b0, s0, 0, 0, 0);
            }
#pragma unroll
            for (int k0 = 0; k0 < 8; k0++) {
                bf16x8 b1 = *(const bf16x8*)(&Kl[16 + ln][k0 * 32 + quad * 8]);
                s1 = __builtin_amdgcn_mfma_f32_16x16x32_bf16(qf[k0], b1, s1, 0, 0, 0);
            }

            const bool full = (p0 + 31 <= imin) && (p0 >= imax - WIN + 1);
#pragma unroll
            for (int r = 0; r < 4; r++) {
                float z0 = __expf(s0[r] * 0.04f);
                float z1 = __expf(s1[r] * 0.04f);
                float t0 = fmaf(-100.f, __builtin_amdgcn_rcpf(z0 + 1.f), 50.f);
                float t1 = fmaf(-100.f, __builtin_amdgcn_rcpf(z1 + 1.f), 50.f);
                float p0v = __expf(t0);
                float p1v = __expf(t1);
                if (!full) {
                    const int i = irow + r;
                    int j0 = p0 + ln, j1 = p0 + 16 + ln;
                    p0v = ((j0 <= i) && (j0 + WIN > i)) ? p0v : 0.f;
                    p1v = ((j1 <= i) && (j1 + WIN > i)) ? p1v : 0.f;
                }
                ps[r] += p0v + p1v;
                Pl[wid][quad * 4 + r][ln] = f2bf(p0v);
                Pl[wid][quad * 4 + r][16 + ln] = f2bf(p1v);
            }
            bf16x8 pa = *(const bf16x8*)(&Pl[wid][ln][quad * 8]);
#pragma unroll
            for (int t = 0; t < 16; t++) {
                bf16x8 vb = *(const bf16x8*)(&Vt[t * 16 + ln][quad * 8]);
                acc[t] = __builtin_amdgcn_mfma_f32_16x16x32_bf16(pa, vb, acc[t], 0, 0, 0);
            }
        }
        __syncthreads();
    }

    // reduce ps over the 16 lanes of each quad-group
    float psr[4];
#pragma unroll
    for (int r = 0; r < 4; r++) {
        float s = ps[r];
#pragma unroll
        for (int o = 1; o <= 8; o <<= 1)
            s += __shfl_xor(s, o);
        psr[r] = s;
    }

    if (nc == 1) {
#pragma unroll
        for (int t = 0; t < 16; t++) {
#pragma unroll
            for (int r = 0; r < 4; r++) {
                float o = acc[t][r] * __builtin_amdgcn_rcpf(psr[r]);
                attn_out[(size_t)(irow + r) * 4096 + h * HDIM + t * 16 + ln] = f2bf(o);
            }
        }
    } else {
        if (ln == 0) {
#pragma unroll
            for (int r = 0; r < 4; r++)
                atomicAdd(&Ps[h * S_LEN + irow + r], psr[r]);
        }
#pragma unroll
        for (int t = 0; t < 16; t++) {
#pragma unroll
            for (int r = 0; r < 4; r++)
                atomicAdd(&Acc[((size_t)h * S_LEN + irow + r) * HDIM + t * 16 + ln], acc[t][r]);
        }
    }
}

// ---------------- normalize chunked rows (pos >= 1024) ----------------
__global__ __launch_bounds__(256) void norm_kernel(const float* __restrict__ Acc,
                                                   const float* __restrict__ Ps,
                                                   unsigned short* __restrict__ attn_out) {
    int row = blockIdx.x * 4 + (threadIdx.x >> 6);   // over 16*2048 rows
    int lane = threadIdx.x & 63;
    int h = row >> 11;
    int pos = 1024 + (row & 2047);
    float4 a = *(const float4*)(Acc + ((size_t)h * S_LEN + pos) * HDIM + lane * 4);
    float inv = __builtin_amdgcn_rcpf(Ps[h * S_LEN + pos]);
    ushort4 o;
    o.x = f2bf(a.x * inv); o.y = f2bf(a.y * inv);
    o.z = f2bf(a.z * inv); o.w = f2bf(a.w * inv);
    *(ushort4*)(attn_out + (size_t)pos * 4096 + h * HDIM + lane * 4) = o;
}

// ---------------- launch ----------------
extern "C" void kernel_launch(void* const* d_in, const int* in_sizes, int n_in,
                              void* d_out, int out_size, void* d_ws, size_t ws_size,
                              hipStream_t stream) {
    (void)in_sizes; (void)n_in; (void)out_size; (void)ws_size;
    const float* hidden = (const float*)d_in[0];
    const float* freqs  = (const float*)d_in[1];
    const int* kvidx    = (const int*)d_in[2];
    const float* qkv_w  = (const float*)d_in[6];
    const float* o_w    = (const float*)d_in[7];
    float* out = (float*)d_out;

    char* ws = (char*)d_ws;
    unsigned short* hs_bf   = (unsigned short*)(ws);                 // 22.0 MB (gemm1 input; Ps reuses after)
    unsigned short* w1_bf   = (unsigned short*)(ws + 22020096);
    unsigned short* w2_bf   = (unsigned short*)(ws + 80740352);
    unsigned short* qkv_bf  = (unsigned short*)(ws + 110100480);     // 50.3 MB (Acc reuses after rope/vtrans)
    unsigned short* Qb      = (unsigned short*)(ws + 160432128);
    unsigned short* Kb      = (unsigned short*)(ws + 185597952);
    unsigned short* Vbt     = (unsigned short*)(ws + 198180864);
    unsigned short* attn_bf = (unsigned short*)(ws + 210763776);

    float* Acc = (float*)(ws + 110100480);   // 16*3072*256*4 = 50,331,648 B exactly
    float* Ps  = (float*)(ws);               // 16*3072*4 = 196,608 B (over retired hs_bf)

    cast_bf16_kernel<<<10752, 256, 0, stream>>>(hidden, hs_bf, 11010048);
    cast_bf16_kernel<<<28672, 256, 0, stream>>>(qkv_w, w1_bf, 29360128);
    cast_bf16_kernel<<<14336, 256, 0, stream>>>(o_w, w2_bf, 14680064);

    gemm_bt<1><<<dim3(64, 24), 256, 0, stream>>>(hs_bf, w1_bf, (void*)qkv_bf, 8192, 3584);

    rope_kernel<<<36864, 256, 0, stream>>>(qkv_bf, freqs, kvidx, Qb, Kb);
    vtrans_kernel<<<dim3(48, 32), 256, 0, stream>>>(qkv_bf, kvidx, Vbt);

    // zero partial buffers (regions retired by gemm1/rope/vtrans above)
    hipMemsetAsync(Acc, 0, (size_t)16 * 3072 * 256 * 4, stream);
    hipMemsetAsync(Ps, 0, (size_t)16 * 3072 * 4, stream);

    attn_kernel<<<1536, 256, 0, stream>>>(Qb, Kb, Vbt, Acc, Ps, attn_bf);
    norm_kernel<<<8192, 256, 0, stream>>>(Acc, Ps, attn_bf);

    gemm_bt<0><<<dim3(28, 24), 256, 0, stream>>>(attn_bf, w2_bf, (void*)out, 3584, 4096);
}